// Round 9
// baseline (296.041 us; speedup 1.0000x reference)
//
#include <hip/hip_runtime.h>
#include <hip/hip_bf16.h>

typedef __bf16  v8bf __attribute__((ext_vector_type(8)));
typedef float   v4f  __attribute__((ext_vector_type(4)));
typedef float   f4   __attribute__((ext_vector_type(4)));
typedef unsigned short us8 __attribute__((ext_vector_type(8)));
typedef unsigned short us4 __attribute__((ext_vector_type(4)));
typedef unsigned int u32;

#define BATCH 32
#define CDIM  256
#define HW    1024

__device__ inline unsigned short f2u(float x) {
    __hip_bfloat16 h = __float2bfloat16(x);
    union { __hip_bfloat16 h; unsigned short u; } cv; cv.h = h; return cv.u;
}
__device__ inline float u2f(unsigned short u) {
    union { unsigned short u; __hip_bfloat16 h; } cv; cv.u = u; return __bfloat162float(cv.h);
}
__device__ inline float sigmoidf_(float x) {
    x = fminf(fmaxf(x, -30.f), 30.f);
    return 1.f / (1.f + __expf(-x));
}
__device__ inline float tanhf_(float x) {
    x = fminf(fmaxf(x, -15.f), 15.f);
    float e = __expf(2.f * x);
    return (e - 1.f) / (e + 1.f);
}
// direct global->LDS DMA, 16B per lane; lds dest is wave-uniform base + lane*16
__device__ inline void glds16(const unsigned short* g, unsigned short* l) {
    __builtin_amdgcn_global_load_lds(
        (const __attribute__((address_space(1))) u32*)g,
        (__attribute__((address_space(3))) u32*)l, 16, 0, 0);
}

// ---------------------------------------------------------------------------
// Weight pack: fp32 -> bf16 concatenated + Wz^T + Wf h-columns + biases.
// ---------------------------------------------------------------------------
__global__ __launch_bounds__(256)
void pack_weights(const float* __restrict__ Wq, const float* __restrict__ Wk,
                  const float* __restrict__ Wv, const float* __restrict__ Wk2,
                  const float* __restrict__ Wv2, const float* __restrict__ Wz,
                  const float* __restrict__ Wm,
                  const float* __restrict__ bq, const float* __restrict__ bk,
                  const float* __restrict__ bk2, const float* __restrict__ bv,
                  const float* __restrict__ bv2, const float* __restrict__ bz,
                  const float* __restrict__ bm,
                  unsigned short* __restrict__ wdst, float* __restrict__ bdst)
{
    const int gid = blockIdx.x * 256 + threadIdx.x;
    if (gid < 1081344) {
        const float* s; int off;
        if      (gid <   32768) { s = Wq;  off = gid; }
        else if (gid <   65536) { s = Wk;  off = gid -   32768; }
        else if (gid <   98304) { s = Wk2; off = gid -   65536; }
        else if (gid <  163840) { s = Wv;  off = gid -   98304; }
        else if (gid <  229376) { s = Wv2; off = gid -  163840; }
        else if (gid <  491520) { s = Wz;  off = gid -  229376; }
        else                    { s = Wm;  off = gid -  491520; }
        wdst[gid] = f2u(s[off]);
    } else if (gid < 1343488) {
        const int idx = gid - 1081344;          // WzT[k][j] = Wz[j][k]
        const int k = idx >> 9, j = idx & 511;
        wdst[gid] = f2u(Wz[j * 512 + k]);
    } else if (gid < 1540096) {
        const int idx = gid - 1343488;          // Wf[o][512+r] = Wm[o][512+r]
        const int o = idx >> 8, kk = 512 + (idx & 255);
        wdst[1343488 + o * 768 + kk] = f2u(Wm[o * 768 + kk]);
    } else {
        const int bi = gid - 1540096;
        if (bi < 2176) {
            const float* s; int off;
            if      (bi <  128) { s = bq;  off = bi; }
            else if (bi <  256) { s = bk;  off = bi -  128; }
            else if (bi <  384) { s = bk2; off = bi -  256; }
            else if (bi <  640) { s = bv;  off = bi -  384; }
            else if (bi <  896) { s = bv2; off = bi -  640; }
            else if (bi < 1408) { s = bz;  off = bi -  896; }
            else                { s = bm;  off = bi - 1408; }
            bdst[bi] = s[off];
        }
    }
}

// ---------------------------------------------------------------------------
// bfused[o] = bm[o] + sum_{j<512} Wm[o][j] * bz[j]   (fp32, exact inputs)
// ---------------------------------------------------------------------------
__global__ __launch_bounds__(256)
void fuse_bias(const float* __restrict__ Wm, const float* __restrict__ bz,
               const float* __restrict__ bm, float* __restrict__ out)
{
    const int o = blockIdx.x * 256 + threadIdx.x;
    if (o >= 768) return;
    float s = bm[o];
    const float* r = Wm + (long)o * 768;
#pragma unroll 8
    for (int j = 0; j < 512; ++j) s += r[j] * bz[j];
    out[o] = s;
}

// ---------------------------------------------------------------------------
// Transposing fp32->bf16 convert: x[b][c][p] -> xT[b][p][c].
// ---------------------------------------------------------------------------
__global__ __launch_bounds__(256)
void transpose_cvt(const float* __restrict__ hsrc, const float* __restrict__ msrc,
                   unsigned short* __restrict__ hT, unsigned short* __restrict__ mT)
{
    const int z = blockIdx.z;
    const float* src = (z < BATCH) ? hsrc + (long)z * CDIM * HW
                                   : msrc + (long)(z - BATCH) * CDIM * HW;
    unsigned short* dst = (z < BATCH) ? hT + (long)z * HW * CDIM
                                      : mT + (long)(z - BATCH) * HW * CDIM;
    const int p0 = blockIdx.x * 64;
    const int c0 = blockIdx.y * 64;
    __shared__ float t[64][68];
    const int tid = threadIdx.x;
    const int r  = tid >> 4;
    const int c4 = (tid & 15) * 4;
#pragma unroll
    for (int i = 0; i < 4; ++i) {
        const f4 v = *reinterpret_cast<const f4*>(src + (long)(c0 + r + 16 * i) * HW + p0 + c4);
        t[r + 16 * i][c4 + 0] = v[0];
        t[r + 16 * i][c4 + 1] = v[1];
        t[r + 16 * i][c4 + 2] = v[2];
        t[r + 16 * i][c4 + 3] = v[3];
    }
    __syncthreads();
#pragma unroll
    for (int i = 0; i < 4; ++i) {
        const int pr = r + 16 * i;
        us4 o;
#pragma unroll
        for (int j = 0; j < 4; ++j) o[j] = f2u(t[c4 + j][pr]);
        *reinterpret_cast<us4*>(dst + (long)(p0 + pr) * CDIM + c0 + c4) = o;
    }
}

// ---------------------------------------------------------------------------
// Shared GEMM core: 128x128 tile, BK=64, st-swizzled LDS (linear dest,
// inverse-swizzled global source, swizzled ds_read).
// ---------------------------------------------------------------------------
__device__ __forceinline__
void gemm_core(const unsigned short* __restrict__ A, int lda,
               const unsigned short* __restrict__ A2, int lda2, int kswitch,
               const unsigned short* __restrict__ Bt, int ldb,
               unsigned short* __restrict__ Cp, int ldc,
               int K, const float* __restrict__ bias, int biasMode,
               int m0, int n0,
               unsigned short* As, unsigned short* Bs)
{
    const int tid  = threadIdx.x;
    const int lane = tid & 63;
    const int w    = tid >> 6;

    v4f acc[4][4];
#pragma unroll
    for (int i = 0; i < 4; ++i)
#pragma unroll
        for (int j = 0; j < 4; ++j) acc[i][j] = v4f{0.f, 0.f, 0.f, 0.f};

    const int wm   = (w >> 1) * 64;
    const int wn   = (w & 1) * 64;
    const int fr   = lane & 15;
    const int g    = lane >> 4;

    const int arow = (w << 3) + (lane >> 3);
    const int acol = (((lane & 7) ^ ((lane >> 3) & 7)) * 8);
    const int lbase = (w << 9);

    for (int k0 = 0; k0 < K; k0 += 64) {
        const unsigned short* Ab; int Al; int Ao;
        if (k0 < kswitch) { Ab = A;  Al = lda;  Ao = k0; }
        else              { Ab = A2; Al = lda2; Ao = k0 - kswitch; }
        const unsigned short* ga = Ab + (long)(m0 + arow) * Al + Ao + acol;
        const unsigned short* gb = Bt + (long)(n0 + arow) * ldb + k0 + acol;
#pragma unroll
        for (int i = 0; i < 4; ++i) {
            glds16(ga + (long)(32 * i) * Al, &As[i * 2048 + lbase]);
            glds16(gb + (long)(32 * i) * ldb, &Bs[i * 2048 + lbase]);
        }
        __syncthreads();
#pragma unroll
        for (int ks = 0; ks < 2; ++ks) {
            const int slot = ((ks * 4 + g) ^ (fr & 7)) * 8;
            v8bf af[4], bfv[4];
#pragma unroll
            for (int mi = 0; mi < 4; ++mi)
                af[mi] = *reinterpret_cast<const v8bf*>(&As[(wm + mi * 16 + fr) * 64 + slot]);
#pragma unroll
            for (int ni = 0; ni < 4; ++ni)
                bfv[ni] = *reinterpret_cast<const v8bf*>(&Bs[(wn + ni * 16 + fr) * 64 + slot]);
#pragma unroll
            for (int mi = 0; mi < 4; ++mi)
#pragma unroll
                for (int ni = 0; ni < 4; ++ni)
                    acc[mi][ni] = __builtin_amdgcn_mfma_f32_16x16x32_bf16(af[mi], bfv[ni], acc[mi][ni], 0, 0, 0);
        }
        __syncthreads();
    }

    const int rbase0 = m0 + wm + g * 4;
#pragma unroll
    for (int mi = 0; mi < 4; ++mi) {
#pragma unroll
        for (int ni = 0; ni < 4; ++ni) {
            const int col = n0 + wn + ni * 16 + fr;
            const int rb  = rbase0 + mi * 16;
            const float bn = (biasMode == 1) ? bias[col] : 0.f;
#pragma unroll
            for (int r = 0; r < 4; ++r) {
                float x = acc[mi][ni][r] + bn;
                if (biasMode == 2) x += bias[rb + r];
                Cp[(long)(rb + r) * ldc + col] = f2u(x);
            }
        }
    }
}

__global__ __launch_bounds__(256)
void gemm_bf16(const unsigned short* __restrict__ A, int lda, long sA,
               const unsigned short* __restrict__ A2, int lda2, long sA2, int kswitch,
               const unsigned short* __restrict__ Bt, int ldb, long sB,
               unsigned short* __restrict__ Cp, int ldc, long sC,
               int K, const float* __restrict__ bias, int biasMode)
{
    __shared__ unsigned short As[128 * 64];
    __shared__ unsigned short Bs[128 * 64];
    const int b = blockIdx.z;
    gemm_core(A + (long)b * sA, lda, A2 + (long)b * sA2, lda2, kswitch,
              Bt + (long)b * sB, ldb, Cp + (long)b * sC, ldc,
              K, bias, biasMode, blockIdx.x * 128, blockIdx.y * 128, As, Bs);
}

// Two independent batched GEMM jobs in one dispatch.
__global__ __launch_bounds__(256)
void gemm_pair(const unsigned short* __restrict__ A0, int lda0, long sA0,
               const unsigned short* __restrict__ B0, int ldb0, long sB0,
               unsigned short* __restrict__ C0, int ldc0, long sC0,
               const float* __restrict__ bias0, int bm0,
               const unsigned short* __restrict__ A1, int lda1, long sA1,
               const unsigned short* __restrict__ B1, int ldb1, long sB1,
               unsigned short* __restrict__ C1, int ldc1, long sC1,
               const float* __restrict__ bias1, int bm1,
               int K, int ny1)
{
    __shared__ unsigned short As[128 * 64];
    __shared__ unsigned short Bs[128 * 64];
    const int z = blockIdx.z;
    if (z < 32) {
        gemm_core(A0 + (long)z * sA0, lda0, A0, lda0, 1 << 30,
                  B0 + (long)z * sB0, ldb0, C0 + (long)z * sC0, ldc0,
                  K, bias0, bm0, blockIdx.x * 128, blockIdx.y * 128, As, Bs);
    } else {
        if ((int)blockIdx.y >= ny1) return;
        const int b = z - 32;
        gemm_core(A1 + (long)b * sA1, lda1, A1, lda1, 1 << 30,
                  B1 + (long)b * sB1, ldb1, C1 + (long)b * sC1, ldc1,
                  K, bias1, bm1, blockIdx.x * 128, blockIdx.y * 128, As, Bs);
    }
}

// ---------------------------------------------------------------------------
// Fused attention v5: single barrier per kv-step (T15-style pipeline).
// K dbuf (staged 2 ahead), V dbuf (1 ahead), P dbuf. Per iteration t:
//   barrier -> stage K(t+2)->K[t&1], V(t+1)->V[(t+1)&1]
//           -> S(t+1) from K[(t+1)&1] -> exp -> Ps[(t+1)&1]   (t<15)
//           -> PV(t) from Ps[t&1], V[t&1]
// S(t+1) and PV(t) are independent MFMA chains in ONE issue window; exp
// overlaps PV's matrix work. All stages drain a full step after issue.
// LDS 128KB; XCD-locality swizzled 1D grid (R7: FETCH 205->33MB).
// (512,2): 256-reg budget — tighter bounds spill qf/vacc (R6 disaster).
// ---------------------------------------------------------------------------
__global__ __launch_bounds__(512, 2)
void attn_fused(const unsigned short* __restrict__ Qb, long sQ, int ldq,
                const unsigned short* __restrict__ K0, long sK0, int ldk0,
                const unsigned short* __restrict__ V0,
                const unsigned short* __restrict__ K1, long sK1, int ldk1,
                const unsigned short* __restrict__ V1,
                unsigned short* __restrict__ Out, long sO)
{
    __shared__ unsigned short Ks[2][64 * 128];   // 2 x 16 KB
    __shared__ unsigned short Vs[2][256 * 64];   // 2 x 32 KB
    __shared__ unsigned short Ps[2][128 * 64];   // 2 x 16 KB

    const int id = blockIdx.x;            // 0..511
    const int c8 = id & 7;
    const int k  = id >> 3;               // 0..63
    const int z  = c8 * 8 + (k >> 3);     // (branch,batch)
    const int p0 = (k & 7) * 128;

    const int b  = (z < 32) ? z : z - 32;
    const unsigned short* Kp; const unsigned short* Vp; int ldk, outoff;
    if (z < 32) { Kp = K0 + (long)b * sK0; Vp = V0 + (long)b * 262144L; ldk = ldk0; outoff = 0; }
    else        { Kp = K1 + (long)b * sK1; Vp = V1 + (long)b * 262144L; ldk = ldk1; outoff = 256; }
    const unsigned short* Qp = Qb + (long)b * sQ;
    Out += (long)b * sO;

    const int tid  = threadIdx.x;
    const int lane = tid & 63;
    const int w    = tid >> 6;
    const int fr   = lane & 15;
    const int g    = lane >> 4;
    const int wp   = w >> 2;     // p-half
    const int wq   = w & 3;      // kv-quarter (S) / c-quarter (PV)

    v8bf qf[4][4];
#pragma unroll
    for (int mi = 0; mi < 4; ++mi)
#pragma unroll
        for (int ks = 0; ks < 4; ++ks)
            qf[mi][ks] = *reinterpret_cast<const v8bf*>(
                Qp + (long)(p0 + wp * 64 + mi * 16 + fr) * ldq + ks * 32 + g * 8);

    v4f vacc[4][4];
#pragma unroll
    for (int i = 0; i < 4; ++i)
#pragma unroll
        for (int j = 0; j < 4; ++j) vacc[i][j] = v4f{0.f, 0.f, 0.f, 0.f};
    float rp[4][4];
#pragma unroll
    for (int i = 0; i < 4; ++i)
#pragma unroll
        for (int r = 0; r < 4; ++r) rp[i][r] = 0.f;

    const int krow   = tid >> 4;
    const int kchunk = ((tid & 15) ^ (krow & 7)) * 8;
    const int vrow   = tid >> 3;
    const int vchunk = ((tid & 7) ^ (vrow & 7)) * 8;
    const int sdst   = w * 512;
    const int kr     = wq * 16 + fr;

#define STAGE_K(t, bi)                                                         \
    { const int kv0 = (t) * 64;                                                \
      _Pragma("unroll")                                                        \
      for (int i = 0; i < 2; ++i)                                              \
          glds16(Kp + (long)(kv0 + i * 32 + krow) * ldk + kchunk,              \
                 &Ks[bi][i * 4096 + sdst]); }
#define STAGE_V(t, bi)                                                         \
    { const int kv0 = (t) * 64;                                                \
      _Pragma("unroll")                                                        \
      for (int i = 0; i < 4; ++i)                                              \
          glds16(Vp + (long)(i * 64 + vrow) * 1024 + kv0 + vchunk,             \
                 &Vs[bi][i * 4096 + sdst]); }

// S-phase for kv-tile tt: QK^T (64p x 16kv per wave) -> exp -> Ps[tt&1]
#define S_PHASE(tt)                                                            \
    {                                                                          \
        const unsigned short* Kr = Ks[(tt) & 1];                               \
        unsigned short* Pw = Ps[(tt) & 1];                                     \
        v4f sacc[4];                                                           \
        _Pragma("unroll")                                                      \
        for (int mi = 0; mi < 4; ++mi) sacc[mi] = v4f{0.f, 0.f, 0.f, 0.f};     \
        __builtin_amdgcn_s_setprio(1);                                         \
        _Pragma("unroll")                                                      \
        for (int ks = 0; ks < 4; ++ks) {                                       \
            const v8bf kf = *reinterpret_cast<const v8bf*>(                    \
                &Kr[kr * 128 + ((ks * 4 + g) ^ (kr & 7)) * 8]);                \
            _Pragma("unroll")                                                  \
            for (int mi = 0; mi < 4; ++mi)                                     \
                sacc[mi] = __builtin_amdgcn_mfma_f32_16x16x32_bf16(            \
                    qf[mi][ks], kf, sacc[mi], 0, 0, 0);                        \
        }                                                                      \
        __builtin_amdgcn_s_setprio(0);                                         \
        _Pragma("unroll")                                                      \
        for (int mi = 0; mi < 4; ++mi)                                         \
            _Pragma("unroll")                                                  \
            for (int r = 0; r < 4; ++r) {                                      \
                const float e = __expf(sacc[mi][r]);                           \
                rp[mi][r] += e;                                                \
                const int prow = wp * 64 + mi * 16 + g * 4 + r;                \
                Pw[prow * 64 + (kr ^ ((prow & 7) << 3))] = f2u(e);             \
            }                                                                  \
    }

// PV-phase for kv-tile tt: vacc += P @ V^T (64p x 64c per wave, K=64)
#define PV_PHASE(tt)                                                           \
    {                                                                          \
        const unsigned short* Pr = Ps[(tt) & 1];                               \
        const unsigned short* Vr = Vs[(tt) & 1];                               \
        __builtin_amdgcn_s_setprio(1);                                         \
        _Pragma("unroll")                                                      \
        for (int ks = 0; ks < 2; ++ks) {                                       \
            v8bf pf[4], vf[4];                                                 \
            _Pragma("unroll")                                                  \
            for (int mi = 0; mi < 4; ++mi) {                                   \
                const int pr = wp * 64 + mi * 16 + fr;                         \
                pf[mi] = *reinterpret_cast<const v8bf*>(                       \
                    &Pr[pr * 64 + ((ks * 4 + g) ^ (pr & 7)) * 8]);             \
            }                                                                  \
            _Pragma("unroll")                                                  \
            for (int ni = 0; ni < 4; ++ni) {                                   \
                const int vr = wq * 64 + ni * 16 + fr;                         \
                vf[ni] = *reinterpret_cast<const v8bf*>(                       \
                    &Vr[vr * 64 + ((ks * 4 + g) ^ (vr & 7)) * 8]);             \
            }                                                                  \
            _Pragma("unroll")                                                  \
            for (int mi = 0; mi < 4; ++mi)                                     \
                _Pragma("unroll")                                              \
                for (int ni = 0; ni < 4; ++ni)                                 \
                    vacc[mi][ni] = __builtin_amdgcn_mfma_f32_16x16x32_bf16(    \
                        pf[mi], vf[ni], vacc[mi][ni], 0, 0, 0);                \
        }                                                                      \
        __builtin_amdgcn_s_setprio(0);                                         \
    }

    // prologue: K(0),V(0) staged; after barrier stage K(1); compute S(0)
    STAGE_K(0, 0);
    STAGE_V(0, 0);
    __syncthreads();          // K(0),V(0) resident
    STAGE_K(1, 1);            // drains at barrier(0), used by S(1)
    S_PHASE(0);               // Ps[0]; visible after barrier(0)

    for (int t = 0; t < 16; ++t) {
        __syncthreads();      // drains stages issued last iter; Ps[t&1] visible
        if (t < 14) STAGE_K(t + 2, t & 1);           // K[t&1] free: S(t) done
        if (t < 15) STAGE_V(t + 1, (t + 1) & 1);     // V[(t+1)&1] free: PV(t-1) done
        if (t < 15) S_PHASE(t + 1);                  // reads K[(t+1)&1] -> Ps[(t+1)&1]
        PV_PHASE(t);                                 // reads Ps[t&1], V[t&1]
    }
#undef STAGE_K
#undef STAGE_V
#undef S_PHASE
#undef PV_PHASE

    __syncthreads();
    float* red = reinterpret_cast<float*>(Ps);
#pragma unroll
    for (int mi = 0; mi < 4; ++mi)
#pragma unroll
        for (int r = 0; r < 4; ++r) {
            float v = rp[mi][r];
            v += __shfl_xor(v, 1);
            v += __shfl_xor(v, 2);
            v += __shfl_xor(v, 4);
            v += __shfl_xor(v, 8);
            if (fr == 0) red[wq * 128 + wp * 64 + mi * 16 + g * 4 + r] = v;
        }
    __syncthreads();

    float inv_[4][4];
#pragma unroll
    for (int mi = 0; mi < 4; ++mi)
#pragma unroll
        for (int r = 0; r < 4; ++r) {
            const int pl = wp * 64 + mi * 16 + g * 4 + r;
            inv_[mi][r] = 1.f / (red[pl] + red[128 + pl] + red[256 + pl] + red[384 + pl]);
        }
#pragma unroll
    for (int mi = 0; mi < 4; ++mi)
#pragma unroll
        for (int ni = 0; ni < 4; ++ni)
#pragma unroll
            for (int r = 0; r < 4; ++r)
                Out[(long)(p0 + wp * 64 + mi * 16 + g * 4 + r) * 512
                    + outoff + wq * 64 + ni * 16 + fr] = f2u(vacc[mi][ni][r] * inv_[mi][r]);
}

// ---------------------------------------------------------------------------
// Gating epilogue.
// ---------------------------------------------------------------------------
__global__ __launch_bounds__(256)
void gating(const unsigned short* __restrict__ combT, const float* __restrict__ m,
            float* __restrict__ outh, float* __restrict__ outm)
{
    const int b  = blockIdx.y;
    const int p0 = blockIdx.x * 32;
    __shared__ unsigned short t[32 * 776];
    const unsigned short* src = combT + ((long)b * HW + p0) * 768;
    const int tid = threadIdx.x;
    for (int i = tid; i < 32 * 96; i += 256) {
        const int rr = i / 96;
        const int cc = (i % 96) * 8;
        *reinterpret_cast<us8*>(&t[rr * 776 + cc]) =
            *reinterpret_cast<const us8*>(src + (long)rr * 768 + cc);
    }
    __syncthreads();
    const int pl = tid & 31;
    const int cl = tid >> 5;
    for (int ci = 0; ci < 32; ++ci) {
        const int c = ci * 8 + cl;
        const float mo = u2f(t[pl * 776 + c]);
        const float mg = u2f(t[pl * 776 + 256 + c]);
        const float mi = u2f(t[pl * 776 + 512 + c]);
        const long gi = ((long)b * CDIM + c) * HW + p0 + pl;
        const float mv = m[gi];
        const float ms = sigmoidf_(mi);
        const float nm = (1.f - ms) * mv + ms * tanhf_(mg);
        const float nh = sigmoidf_(mo) * nm;
        outh[gi] = nh;
        outm[gi] = nm;
    }
}

// ---------------------------------------------------------------------------
extern "C" void kernel_launch(void* const* d_in, const int* in_sizes, int n_in,
                              void* d_out, int out_size, void* d_ws, size_t ws_size,
                              hipStream_t stream)
{
    const float* h   = (const float*)d_in[0];
    const float* m   = (const float*)d_in[1];
    const float* Wq  = (const float*)d_in[2];
    const float* bq  = (const float*)d_in[3];
    const float* Wk  = (const float*)d_in[4];
    const float* bk  = (const float*)d_in[5];
    const float* Wv  = (const float*)d_in[6];
    const float* bv  = (const float*)d_in[7];
    const float* Wk2 = (const float*)d_in[8];
    const float* bk2 = (const float*)d_in[9];
    const float* Wv2 = (const float*)d_in[10];
    const float* bv2 = (const float*)d_in[11];
    const float* Wz  = (const float*)d_in[12];
    const float* bz  = (const float*)d_in[13];
    const float* Wm  = (const float*)d_in[14];
    const float* bm  = (const float*)d_in[15];

    char* ws = (char*)d_ws;
    const long OFF_HBT = 0L;                     // h_bfT [32][1024][256]
    const long OFF_MBT = OFF_HBT + 16777216L;    // m_bfT
    const long OFF_QKH = OFF_MBT + 16777216L;    // qk_h  [32][1024][256]
    const long OFF_QKM = OFF_QKH + 16777216L;    // k2_m  [32][1024][128]
    const long OFF_VH  = OFF_QKM + 8388608L;     // v_h   [32][256][1024]
    const long OFF_VM  = OFF_VH  + 16777216L;    // v_m
    const long OFF_ZCT = OFF_VM  + 16777216L;    // zcatT [32][1024][512]
    const long OFF_W   = OFF_ZCT + 33554432L;    // weights (1933312 shorts)
    const long OFF_B   = OFF_W   + 3866624L;     // biases (2944 floats)
    const long OFF_CMB = OFF_MBT;                // overlay (mT/qkh/qkm/vh dead)
    const long TOTAL   = OFF_B + 2944L * 4;      // 129,707,520 bytes
    if (ws_size < (size_t)TOTAL) return;

    unsigned short* hT  = (unsigned short*)(ws + OFF_HBT);
    unsigned short* mT  = (unsigned short*)(ws + OFF_MBT);
    unsigned short* qkh = (unsigned short*)(ws + OFF_QKH);
    unsigned short* qkm = (unsigned short*)(ws + OFF_QKM);
    unsigned short* vh  = (unsigned short*)(ws + OFF_VH);
    unsigned short* vm  = (unsigned short*)(ws + OFF_VM);
    unsigned short* zct = (unsigned short*)(ws + OFF_ZCT);
    unsigned short* cmb = (unsigned short*)(ws + OFF_CMB);
    unsigned short* wA  = (unsigned short*)(ws + OFF_W);
    float*          bA  = (float*)(ws + OFF_B);

    unsigned short* Wqk_w = wA;
    unsigned short* Wk2_w = wA + 65536;
    unsigned short* Wv_w  = wA + 98304;
    unsigned short* Wv2_w = wA + 163840;
    unsigned short* Wm_w  = wA + 491520;
    unsigned short* WzT_w = wA + 1081344;
    unsigned short* Wf_w  = wA + 1343488;
    float* bqk_w = bA;
    float* bk2_w = bA + 256;
    float* bv_w  = bA + 384;
    float* bv2_w = bA + 640;
    float* bf_w  = bA + 2176;   // fused bias (768)

    float* outh = (float*)d_out;
    float* outm = outh + 8388608L;

    pack_weights<<<dim3(6025), dim3(256), 0, stream>>>(
        Wq, Wk, Wv, Wk2, Wv2, Wz, Wm, bq, bk, bk2, bv, bv2, bz, bm, wA, bA);

    transpose_cvt<<<dim3(16, 4, 64), dim3(256), 0, stream>>>(h, m, hT, mT);

    fuse_bias<<<dim3(3), dim3(256), 0, stream>>>(Wm, bz, bm, bf_w);

    const int BIG = 1 << 30;
    // Wf[:, 0:512] = Wm[:, 0:512] @ Wz
    gemm_bf16<<<dim3(6, 4, 1), dim3(256), 0, stream>>>(
        Wm_w, 768, 0L, Wm_w, 768, 0L, BIG,
        WzT_w, 512, 0L, Wf_w, 768, 0L, 512, bA, 0);

    // projections: [q|k]_h^T + k2_m^T in one dispatch
    gemm_pair<<<dim3(8, 2, 64), dim3(256), 0, stream>>>(
        hT, 256, 262144L, Wqk_w, 256, 0L, qkh, 256, 262144L, bqk_w, 1,
        mT, 256, 262144L, Wk2_w, 256, 0L, qkm, 128, 131072L, bk2_w, 1,
        256, 1);
    // v_h + v_m in one dispatch
    gemm_pair<<<dim3(2, 8, 64), dim3(256), 0, stream>>>(
        Wv_w, 256, 0L, hT, 256, 262144L, vh, 1024, 262144L, bv_w, 2,
        Wv2_w, 256, 0L, mT, 256, 262144L, vm, 1024, 262144L, bv2_w, 2,
        256, 8);

    // fused attention, both branches, XCD-swizzled 1D grid
    attn_fused<<<dim3(512), dim3(512), 0, stream>>>(
        qkh, 262144L, 256,
        qkh + 128, 262144L, 256, vh,
        qkm, 131072L, 128, vm,
        zct, 524288L);

    // comb^T = [zcatT | h^T] @ Wf^T + bfused
    gemm_bf16<<<dim3(8, 6, 32), dim3(256), 0, stream>>>(
        zct, 512, 524288L, hT, 256, 262144L, 512,
        Wf_w, 768, 0L, cmb, 768, 786432L, 768, bf_w, 1);

    gating<<<dim3(32, 32), dim3(256), 0, stream>>>(cmb, m, outh, outm);
}

// Round 10
// 287.914 us; speedup vs baseline: 1.0282x; 1.0282x over previous
//
#include <hip/hip_runtime.h>
#include <hip/hip_bf16.h>

typedef __bf16  v8bf __attribute__((ext_vector_type(8)));
typedef float   v4f  __attribute__((ext_vector_type(4)));
typedef float   f4   __attribute__((ext_vector_type(4)));
typedef unsigned short us8 __attribute__((ext_vector_type(8)));
typedef unsigned short us4 __attribute__((ext_vector_type(4)));
typedef unsigned int u32;

#define BATCH 32
#define CDIM  256
#define HW    1024

__device__ inline unsigned short f2u(float x) {
    __hip_bfloat16 h = __float2bfloat16(x);
    union { __hip_bfloat16 h; unsigned short u; } cv; cv.h = h; return cv.u;
}
__device__ inline float u2f(unsigned short u) {
    union { unsigned short u; __hip_bfloat16 h; } cv; cv.u = u; return __bfloat162float(cv.h);
}
__device__ inline float sigmoidf_(float x) {
    x = fminf(fmaxf(x, -30.f), 30.f);
    return 1.f / (1.f + __expf(-x));
}
__device__ inline float tanhf_(float x) {
    x = fminf(fmaxf(x, -15.f), 15.f);
    float e = __expf(2.f * x);
    return (e - 1.f) / (e + 1.f);
}
// direct global->LDS DMA, 16B per lane; lds dest is wave-uniform base + lane*16
__device__ inline void glds16(const unsigned short* g, unsigned short* l) {
    __builtin_amdgcn_global_load_lds(
        (const __attribute__((address_space(1))) u32*)g,
        (__attribute__((address_space(3))) u32*)l, 16, 0, 0);
}

// ---------------------------------------------------------------------------
// Weight pack: fp32 -> bf16 concatenated + Wz^T + Wf h-columns + biases.
// ---------------------------------------------------------------------------
__global__ __launch_bounds__(256)
void pack_weights(const float* __restrict__ Wq, const float* __restrict__ Wk,
                  const float* __restrict__ Wv, const float* __restrict__ Wk2,
                  const float* __restrict__ Wv2, const float* __restrict__ Wz,
                  const float* __restrict__ Wm,
                  const float* __restrict__ bq, const float* __restrict__ bk,
                  const float* __restrict__ bk2, const float* __restrict__ bv,
                  const float* __restrict__ bv2, const float* __restrict__ bz,
                  const float* __restrict__ bm,
                  unsigned short* __restrict__ wdst, float* __restrict__ bdst)
{
    const int gid = blockIdx.x * 256 + threadIdx.x;
    if (gid < 1081344) {
        const float* s; int off;
        if      (gid <   32768) { s = Wq;  off = gid; }
        else if (gid <   65536) { s = Wk;  off = gid -   32768; }
        else if (gid <   98304) { s = Wk2; off = gid -   65536; }
        else if (gid <  163840) { s = Wv;  off = gid -   98304; }
        else if (gid <  229376) { s = Wv2; off = gid -  163840; }
        else if (gid <  491520) { s = Wz;  off = gid -  229376; }
        else                    { s = Wm;  off = gid -  491520; }
        wdst[gid] = f2u(s[off]);
    } else if (gid < 1343488) {
        const int idx = gid - 1081344;          // WzT[k][j] = Wz[j][k]
        const int k = idx >> 9, j = idx & 511;
        wdst[gid] = f2u(Wz[j * 512 + k]);
    } else if (gid < 1540096) {
        const int idx = gid - 1343488;          // Wf[o][512+r] = Wm[o][512+r]
        const int o = idx >> 8, kk = 512 + (idx & 255);
        wdst[1343488 + o * 768 + kk] = f2u(Wm[o * 768 + kk]);
    } else {
        const int bi = gid - 1540096;
        if (bi < 2176) {
            const float* s; int off;
            if      (bi <  128) { s = bq;  off = bi; }
            else if (bi <  256) { s = bk;  off = bi -  128; }
            else if (bi <  384) { s = bk2; off = bi -  256; }
            else if (bi <  640) { s = bv;  off = bi -  384; }
            else if (bi <  896) { s = bv2; off = bi -  640; }
            else if (bi < 1408) { s = bz;  off = bi -  896; }
            else                { s = bm;  off = bi - 1408; }
            bdst[bi] = s[off];
        }
    }
}

// ---------------------------------------------------------------------------
// bfused[o] = bm[o] + sum_{j<512} Wm[o][j] * bz[j]   (fp32, exact inputs)
// ---------------------------------------------------------------------------
__global__ __launch_bounds__(256)
void fuse_bias(const float* __restrict__ Wm, const float* __restrict__ bz,
               const float* __restrict__ bm, float* __restrict__ out)
{
    const int o = blockIdx.x * 256 + threadIdx.x;
    if (o >= 768) return;
    float s = bm[o];
    const float* r = Wm + (long)o * 768;
#pragma unroll 8
    for (int j = 0; j < 512; ++j) s += r[j] * bz[j];
    out[o] = s;
}

// ---------------------------------------------------------------------------
// Transposing fp32->bf16 convert: x[b][c][p] -> xT[b][p][c].
// ---------------------------------------------------------------------------
__global__ __launch_bounds__(256)
void transpose_cvt(const float* __restrict__ hsrc, const float* __restrict__ msrc,
                   unsigned short* __restrict__ hT, unsigned short* __restrict__ mT)
{
    const int z = blockIdx.z;
    const float* src = (z < BATCH) ? hsrc + (long)z * CDIM * HW
                                   : msrc + (long)(z - BATCH) * CDIM * HW;
    unsigned short* dst = (z < BATCH) ? hT + (long)z * HW * CDIM
                                      : mT + (long)(z - BATCH) * HW * CDIM;
    const int p0 = blockIdx.x * 64;
    const int c0 = blockIdx.y * 64;
    __shared__ float t[64][68];
    const int tid = threadIdx.x;
    const int r  = tid >> 4;
    const int c4 = (tid & 15) * 4;
#pragma unroll
    for (int i = 0; i < 4; ++i) {
        const f4 v = *reinterpret_cast<const f4*>(src + (long)(c0 + r + 16 * i) * HW + p0 + c4);
        t[r + 16 * i][c4 + 0] = v[0];
        t[r + 16 * i][c4 + 1] = v[1];
        t[r + 16 * i][c4 + 2] = v[2];
        t[r + 16 * i][c4 + 3] = v[3];
    }
    __syncthreads();
#pragma unroll
    for (int i = 0; i < 4; ++i) {
        const int pr = r + 16 * i;
        us4 o;
#pragma unroll
        for (int j = 0; j < 4; ++j) o[j] = f2u(t[c4 + j][pr]);
        *reinterpret_cast<us4*>(dst + (long)(p0 + pr) * CDIM + c0 + c4) = o;
    }
}

// ---------------------------------------------------------------------------
// Shared GEMM core: 128x128 tile, BK=64, st-swizzled LDS (linear dest,
// inverse-swizzled global source, swizzled ds_read).
// ---------------------------------------------------------------------------
__device__ __forceinline__
void gemm_core(const unsigned short* __restrict__ A, int lda,
               const unsigned short* __restrict__ A2, int lda2, int kswitch,
               const unsigned short* __restrict__ Bt, int ldb,
               unsigned short* __restrict__ Cp, int ldc,
               int K, const float* __restrict__ bias, int biasMode,
               int m0, int n0,
               unsigned short* As, unsigned short* Bs)
{
    const int tid  = threadIdx.x;
    const int lane = tid & 63;
    const int w    = tid >> 6;

    v4f acc[4][4];
#pragma unroll
    for (int i = 0; i < 4; ++i)
#pragma unroll
        for (int j = 0; j < 4; ++j) acc[i][j] = v4f{0.f, 0.f, 0.f, 0.f};

    const int wm   = (w >> 1) * 64;
    const int wn   = (w & 1) * 64;
    const int fr   = lane & 15;
    const int g    = lane >> 4;

    const int arow = (w << 3) + (lane >> 3);
    const int acol = (((lane & 7) ^ ((lane >> 3) & 7)) * 8);
    const int lbase = (w << 9);

    for (int k0 = 0; k0 < K; k0 += 64) {
        const unsigned short* Ab; int Al; int Ao;
        if (k0 < kswitch) { Ab = A;  Al = lda;  Ao = k0; }
        else              { Ab = A2; Al = lda2; Ao = k0 - kswitch; }
        const unsigned short* ga = Ab + (long)(m0 + arow) * Al + Ao + acol;
        const unsigned short* gb = Bt + (long)(n0 + arow) * ldb + k0 + acol;
#pragma unroll
        for (int i = 0; i < 4; ++i) {
            glds16(ga + (long)(32 * i) * Al, &As[i * 2048 + lbase]);
            glds16(gb + (long)(32 * i) * ldb, &Bs[i * 2048 + lbase]);
        }
        __syncthreads();
#pragma unroll
        for (int ks = 0; ks < 2; ++ks) {
            const int slot = ((ks * 4 + g) ^ (fr & 7)) * 8;
            v8bf af[4], bfv[4];
#pragma unroll
            for (int mi = 0; mi < 4; ++mi)
                af[mi] = *reinterpret_cast<const v8bf*>(&As[(wm + mi * 16 + fr) * 64 + slot]);
#pragma unroll
            for (int ni = 0; ni < 4; ++ni)
                bfv[ni] = *reinterpret_cast<const v8bf*>(&Bs[(wn + ni * 16 + fr) * 64 + slot]);
#pragma unroll
            for (int mi = 0; mi < 4; ++mi)
#pragma unroll
                for (int ni = 0; ni < 4; ++ni)
                    acc[mi][ni] = __builtin_amdgcn_mfma_f32_16x16x32_bf16(af[mi], bfv[ni], acc[mi][ni], 0, 0, 0);
        }
        __syncthreads();
    }

    const int rbase0 = m0 + wm + g * 4;
#pragma unroll
    for (int mi = 0; mi < 4; ++mi) {
#pragma unroll
        for (int ni = 0; ni < 4; ++ni) {
            const int col = n0 + wn + ni * 16 + fr;
            const int rb  = rbase0 + mi * 16;
            const float bn = (biasMode == 1) ? bias[col] : 0.f;
#pragma unroll
            for (int r = 0; r < 4; ++r) {
                float x = acc[mi][ni][r] + bn;
                if (biasMode == 2) x += bias[rb + r];
                Cp[(long)(rb + r) * ldc + col] = f2u(x);
            }
        }
    }
}

__global__ __launch_bounds__(256)
void gemm_bf16(const unsigned short* __restrict__ A, int lda, long sA,
               const unsigned short* __restrict__ A2, int lda2, long sA2, int kswitch,
               const unsigned short* __restrict__ Bt, int ldb, long sB,
               unsigned short* __restrict__ Cp, int ldc, long sC,
               int K, const float* __restrict__ bias, int biasMode)
{
    __shared__ unsigned short As[128 * 64];
    __shared__ unsigned short Bs[128 * 64];
    const int b = blockIdx.z;
    gemm_core(A + (long)b * sA, lda, A2 + (long)b * sA2, lda2, kswitch,
              Bt + (long)b * sB, ldb, Cp + (long)b * sC, ldc,
              K, bias, biasMode, blockIdx.x * 128, blockIdx.y * 128, As, Bs);
}

// Two independent batched GEMM jobs in one dispatch.
__global__ __launch_bounds__(256)
void gemm_pair(const unsigned short* __restrict__ A0, int lda0, long sA0,
               const unsigned short* __restrict__ B0, int ldb0, long sB0,
               unsigned short* __restrict__ C0, int ldc0, long sC0,
               const float* __restrict__ bias0, int bm0,
               const unsigned short* __restrict__ A1, int lda1, long sA1,
               const unsigned short* __restrict__ B1, int ldb1, long sB1,
               unsigned short* __restrict__ C1, int ldc1, long sC1,
               const float* __restrict__ bias1, int bm1,
               int K, int ny1)
{
    __shared__ unsigned short As[128 * 64];
    __shared__ unsigned short Bs[128 * 64];
    const int z = blockIdx.z;
    if (z < 32) {
        gemm_core(A0 + (long)z * sA0, lda0, A0, lda0, 1 << 30,
                  B0 + (long)z * sB0, ldb0, C0 + (long)z * sC0, ldc0,
                  K, bias0, bm0, blockIdx.x * 128, blockIdx.y * 128, As, Bs);
    } else {
        if ((int)blockIdx.y >= ny1) return;
        const int b = z - 32;
        gemm_core(A1 + (long)b * sA1, lda1, A1, lda1, 1 << 30,
                  B1 + (long)b * sB1, ldb1, C1 + (long)b * sC1, ldc1,
                  K, bias1, bm1, blockIdx.x * 128, blockIdx.y * 128, As, Bs);
    }
}

// ---------------------------------------------------------------------------
// Fused attention v6: occupancy-first. 64-p tiles (grid 1024, XCD-swizzled),
// Q in LDS (staged once, -64 VGPR), per-wave tile 32p x 64c (vacc 32 regs).
// LDS 72KB (Q16+K16+V32+P8) -> 2 blocks/CU; __launch_bounds__(512,4) caps
// regs at 128 (state now fits; R6's spill was with ~190-reg state) ->
// 16 waves/CU. R8's proven 2-barrier covered-drain schedule:
//   barrier1 drains K(t) [staged in PV(t-1)];  STAGE_V(t) after it
//   barrier2 drains V(t) [covered by S+exp];   STAGE_K(t+1) after it
// ---------------------------------------------------------------------------
__global__ __launch_bounds__(512, 4)
void attn_fused(const unsigned short* __restrict__ Qb, long sQ, int ldq,
                const unsigned short* __restrict__ K0, long sK0, int ldk0,
                const unsigned short* __restrict__ V0,
                const unsigned short* __restrict__ K1, long sK1, int ldk1,
                const unsigned short* __restrict__ V1,
                unsigned short* __restrict__ Out, long sO)
{
    __shared__ unsigned short Qs[64 * 128];   // 16 KB
    __shared__ unsigned short Ks[64 * 128];   // 16 KB
    __shared__ unsigned short Vs[256 * 64];   // 32 KB
    __shared__ unsigned short Ps[64 * 64];    //  8 KB

    // XCD-locality swizzle: id%8 = XCD; 8 jobs x 16 p-tiles per XCD, tiles
    // of one job consecutive -> K/V hit L2 (R7: FETCH 205->33MB).
    const int id = blockIdx.x;            // 0..1023
    const int c8 = id & 7;
    const int k  = id >> 3;               // 0..127
    const int z  = c8 * 8 + (k >> 4);     // (branch,batch)
    const int p0 = (k & 15) * 64;

    const int b  = (z < 32) ? z : z - 32;
    const unsigned short* Kp; const unsigned short* Vp; int ldk, outoff;
    if (z < 32) { Kp = K0 + (long)b * sK0; Vp = V0 + (long)b * 262144L; ldk = ldk0; outoff = 0; }
    else        { Kp = K1 + (long)b * sK1; Vp = V1 + (long)b * 262144L; ldk = ldk1; outoff = 256; }
    const unsigned short* Qp = Qb + (long)b * sQ;
    Out += (long)b * sO;

    const int tid  = threadIdx.x;
    const int lane = tid & 63;
    const int w    = tid >> 6;
    const int fr   = lane & 15;
    const int g    = lane >> 4;
    const int wp   = w >> 2;     // p-half (32 rows)
    const int wq   = w & 3;      // kv-quarter (S) / c-quarter (PV)

    v4f vacc[2][4];
#pragma unroll
    for (int i = 0; i < 2; ++i)
#pragma unroll
        for (int j = 0; j < 4; ++j) vacc[i][j] = v4f{0.f, 0.f, 0.f, 0.f};
    float rp[2][4];
#pragma unroll
    for (int i = 0; i < 2; ++i)
#pragma unroll
        for (int r = 0; r < 4; ++r) rp[i][r] = 0.f;

    // staging geometry (512 lanes): Q/K 2 calls x 32 rows (128-d rows, 16
    // chunks); V 4 calls x 64 rows (64-q rows, 8 chunks).
    const int srow   = tid >> 4;                          // 0..31
    const int schunk = ((tid & 15) ^ (srow & 7)) * 8;
    const int vrow   = tid >> 3;                          // 0..63
    const int vchunk = ((tid & 7) ^ (vrow & 7)) * 8;
    const int sdst   = w * 512;
    const int kr     = wq * 16 + fr;                      // K row for S

#define STAGE_Q()                                                              \
    { _Pragma("unroll")                                                        \
      for (int i = 0; i < 2; ++i)                                              \
          glds16(Qp + (long)(p0 + i * 32 + srow) * ldq + schunk,               \
                 &Qs[i * 4096 + sdst]); }
#define STAGE_K(t)                                                             \
    { const int kv0 = (t) * 64;                                                \
      _Pragma("unroll")                                                        \
      for (int i = 0; i < 2; ++i)                                              \
          glds16(Kp + (long)(kv0 + i * 32 + srow) * ldk + schunk,              \
                 &Ks[i * 4096 + sdst]); }
#define STAGE_V(t)                                                             \
    { const int kv0 = (t) * 64;                                                \
      _Pragma("unroll")                                                        \
      for (int i = 0; i < 4; ++i)                                              \
          glds16(Vp + (long)(i * 64 + vrow) * 1024 + kv0 + vchunk,             \
                 &Vs[i * 4096 + sdst]); }

    STAGE_Q();
    STAGE_K(0);

    for (int t = 0; t < 16; ++t) {
        __syncthreads();              // drains Q(+K0) / K(t); PV(t-1) LDS reads done
        STAGE_V(t);                   // drained at barrier-2, covered by S+exp

        // ---- S = Q @ K^T (per wave: 32p x 16kv), exp, write P
        v4f sacc[2];
#pragma unroll
        for (int mi = 0; mi < 2; ++mi) sacc[mi] = v4f{0.f, 0.f, 0.f, 0.f};
        __builtin_amdgcn_s_setprio(1);
#pragma unroll
        for (int ks = 0; ks < 4; ++ks) {
            const v8bf kf = *reinterpret_cast<const v8bf*>(
                &Ks[kr * 128 + ((ks * 4 + g) ^ (kr & 7)) * 8]);
#pragma unroll
            for (int mi = 0; mi < 2; ++mi) {
                const int qrow = wp * 32 + mi * 16 + fr;
                const v8bf qf = *reinterpret_cast<const v8bf*>(
                    &Qs[qrow * 128 + ((ks * 4 + g) ^ (qrow & 7)) * 8]);
                sacc[mi] = __builtin_amdgcn_mfma_f32_16x16x32_bf16(qf, kf, sacc[mi], 0, 0, 0);
            }
        }
        __builtin_amdgcn_s_setprio(0);
#pragma unroll
        for (int mi = 0; mi < 2; ++mi)
#pragma unroll
            for (int r = 0; r < 4; ++r) {
                const float e = __expf(sacc[mi][r]);
                rp[mi][r] += e;
                const int prow = wp * 32 + mi * 16 + g * 4 + r;
                Ps[prow * 64 + (kr ^ ((prow & 7) << 3))] = f2u(e);
            }

        __syncthreads();              // drains V(t); Ps visible; Ks reads done
        if (t < 15) STAGE_K(t + 1);   // drained at barrier-1(t+1), covered by PV

        // ---- PV: vacc += P @ V^T (per wave: 32p x 64c, K=64)
        __builtin_amdgcn_s_setprio(1);
#pragma unroll
        for (int ks = 0; ks < 2; ++ks) {
            v8bf pf[2], vf[4];
#pragma unroll
            for (int mi = 0; mi < 2; ++mi) {
                const int pr = wp * 32 + mi * 16 + fr;
                pf[mi] = *reinterpret_cast<const v8bf*>(
                    &Ps[pr * 64 + ((ks * 4 + g) ^ (pr & 7)) * 8]);
            }
#pragma unroll
            for (int ni = 0; ni < 4; ++ni) {
                const int vr = wq * 64 + ni * 16 + fr;
                vf[ni] = *reinterpret_cast<const v8bf*>(
                    &Vs[vr * 64 + ((ks * 4 + g) ^ (vr & 7)) * 8]);
            }
#pragma unroll
            for (int mi = 0; mi < 2; ++mi)
#pragma unroll
                for (int ni = 0; ni < 4; ++ni)
                    vacc[mi][ni] = __builtin_amdgcn_mfma_f32_16x16x32_bf16(pf[mi], vf[ni], vacc[mi][ni], 0, 0, 0);
        }
        __builtin_amdgcn_s_setprio(0);
    }
#undef STAGE_Q
#undef STAGE_K
#undef STAGE_V

    __syncthreads();
    // rowsum: 16 fr-lanes via shfl; 4 wq-waves via LDS (red[4][64] over Ps)
    float* red = reinterpret_cast<float*>(Ps);
#pragma unroll
    for (int mi = 0; mi < 2; ++mi)
#pragma unroll
        for (int r = 0; r < 4; ++r) {
            float v = rp[mi][r];
            v += __shfl_xor(v, 1);
            v += __shfl_xor(v, 2);
            v += __shfl_xor(v, 4);
            v += __shfl_xor(v, 8);
            if (fr == 0) red[wq * 64 + wp * 32 + mi * 16 + g * 4 + r] = v;
        }
    __syncthreads();

#pragma unroll
    for (int mi = 0; mi < 2; ++mi)
#pragma unroll
        for (int r = 0; r < 4; ++r) {
            const int pl = wp * 32 + mi * 16 + g * 4 + r;
            const float inv = 1.f / (red[pl] + red[64 + pl] + red[128 + pl] + red[192 + pl]);
#pragma unroll
            for (int ni = 0; ni < 4; ++ni)
                Out[(long)(p0 + pl) * 512 + outoff + wq * 64 + ni * 16 + fr]
                    = f2u(vacc[mi][ni][r] * inv);
        }
}

// ---------------------------------------------------------------------------
// Gating epilogue.
// ---------------------------------------------------------------------------
__global__ __launch_bounds__(256)
void gating(const unsigned short* __restrict__ combT, const float* __restrict__ m,
            float* __restrict__ outh, float* __restrict__ outm)
{
    const int b  = blockIdx.y;
    const int p0 = blockIdx.x * 32;
    __shared__ unsigned short t[32 * 776];
    const unsigned short* src = combT + ((long)b * HW + p0) * 768;
    const int tid = threadIdx.x;
    for (int i = tid; i < 32 * 96; i += 256) {
        const int rr = i / 96;
        const int cc = (i % 96) * 8;
        *reinterpret_cast<us8*>(&t[rr * 776 + cc]) =
            *reinterpret_cast<const us8*>(src + (long)rr * 768 + cc);
    }
    __syncthreads();
    const int pl = tid & 31;
    const int cl = tid >> 5;
    for (int ci = 0; ci < 32; ++ci) {
        const int c = ci * 8 + cl;
        const float mo = u2f(t[pl * 776 + c]);
        const float mg = u2f(t[pl * 776 + 256 + c]);
        const float mi = u2f(t[pl * 776 + 512 + c]);
        const long gi = ((long)b * CDIM + c) * HW + p0 + pl;
        const float mv = m[gi];
        const float ms = sigmoidf_(mi);
        const float nm = (1.f - ms) * mv + ms * tanhf_(mg);
        const float nh = sigmoidf_(mo) * nm;
        outh[gi] = nh;
        outm[gi] = nm;
    }
}

// ---------------------------------------------------------------------------
extern "C" void kernel_launch(void* const* d_in, const int* in_sizes, int n_in,
                              void* d_out, int out_size, void* d_ws, size_t ws_size,
                              hipStream_t stream)
{
    const float* h   = (const float*)d_in[0];
    const float* m   = (const float*)d_in[1];
    const float* Wq  = (const float*)d_in[2];
    const float* bq  = (const float*)d_in[3];
    const float* Wk  = (const float*)d_in[4];
    const float* bk  = (const float*)d_in[5];
    const float* Wv  = (const float*)d_in[6];
    const float* bv  = (const float*)d_in[7];
    const float* Wk2 = (const float*)d_in[8];
    const float* bk2 = (const float*)d_in[9];
    const float* Wv2 = (const float*)d_in[10];
    const float* bv2 = (const float*)d_in[11];
    const float* Wz  = (const float*)d_in[12];
    const float* bz  = (const float*)d_in[13];
    const float* Wm  = (const float*)d_in[14];
    const float* bm  = (const float*)d_in[15];

    char* ws = (char*)d_ws;
    const long OFF_HBT = 0L;                     // h_bfT [32][1024][256]
    const long OFF_MBT = OFF_HBT + 16777216L;    // m_bfT
    const long OFF_QKH = OFF_MBT + 16777216L;    // qk_h  [32][1024][256]
    const long OFF_QKM = OFF_QKH + 16777216L;    // k2_m  [32][1024][128]
    const long OFF_VH  = OFF_QKM + 8388608L;     // v_h   [32][256][1024]
    const long OFF_VM  = OFF_VH  + 16777216L;    // v_m
    const long OFF_ZCT = OFF_VM  + 16777216L;    // zcatT [32][1024][512]
    const long OFF_W   = OFF_ZCT + 33554432L;    // weights (1933312 shorts)
    const long OFF_B   = OFF_W   + 3866624L;     // biases (2944 floats)
    const long OFF_CMB = OFF_MBT;                // overlay (mT/qkh/qkm/vh dead)
    const long TOTAL   = OFF_B + 2944L * 4;      // 129,707,520 bytes
    if (ws_size < (size_t)TOTAL) return;

    unsigned short* hT  = (unsigned short*)(ws + OFF_HBT);
    unsigned short* mT  = (unsigned short*)(ws + OFF_MBT);
    unsigned short* qkh = (unsigned short*)(ws + OFF_QKH);
    unsigned short* qkm = (unsigned short*)(ws + OFF_QKM);
    unsigned short* vh  = (unsigned short*)(ws + OFF_VH);
    unsigned short* vm  = (unsigned short*)(ws + OFF_VM);
    unsigned short* zct = (unsigned short*)(ws + OFF_ZCT);
    unsigned short* cmb = (unsigned short*)(ws + OFF_CMB);
    unsigned short* wA  = (unsigned short*)(ws + OFF_W);
    float*          bA  = (float*)(ws + OFF_B);

    unsigned short* Wqk_w = wA;
    unsigned short* Wk2_w = wA + 65536;
    unsigned short* Wv_w  = wA + 98304;
    unsigned short* Wv2_w = wA + 163840;
    unsigned short* Wm_w  = wA + 491520;
    unsigned short* WzT_w = wA + 1081344;
    unsigned short* Wf_w  = wA + 1343488;
    float* bqk_w = bA;
    float* bk2_w = bA + 256;
    float* bv_w  = bA + 384;
    float* bv2_w = bA + 640;
    float* bf_w  = bA + 2176;   // fused bias (768)

    float* outh = (float*)d_out;
    float* outm = outh + 8388608L;

    pack_weights<<<dim3(6025), dim3(256), 0, stream>>>(
        Wq, Wk, Wv, Wk2, Wv2, Wz, Wm, bq, bk, bk2, bv, bv2, bz, bm, wA, bA);

    transpose_cvt<<<dim3(16, 4, 64), dim3(256), 0, stream>>>(h, m, hT, mT);

    fuse_bias<<<dim3(3), dim3(256), 0, stream>>>(Wm, bz, bm, bf_w);

    const int BIG = 1 << 30;
    // Wf[:, 0:512] = Wm[:, 0:512] @ Wz
    gemm_bf16<<<dim3(6, 4, 1), dim3(256), 0, stream>>>(
        Wm_w, 768, 0L, Wm_w, 768, 0L, BIG,
        WzT_w, 512, 0L, Wf_w, 768, 0L, 512, bA, 0);

    // projections: [q|k]_h^T + k2_m^T in one dispatch
    gemm_pair<<<dim3(8, 2, 64), dim3(256), 0, stream>>>(
        hT, 256, 262144L, Wqk_w, 256, 0L, qkh, 256, 262144L, bqk_w, 1,
        mT, 256, 262144L, Wk2_w, 256, 0L, qkm, 128, 131072L, bk2_w, 1,
        256, 1);
    // v_h + v_m in one dispatch
    gemm_pair<<<dim3(2, 8, 64), dim3(256), 0, stream>>>(
        Wv_w, 256, 0L, hT, 256, 262144L, vh, 1024, 262144L, bv_w, 2,
        Wv2_w, 256, 0L, mT, 256, 262144L, vm, 1024, 262144L, bv2_w, 2,
        256, 8);

    // fused attention, both branches, XCD-swizzled 1D grid (64-p tiles)
    attn_fused<<<dim3(1024), dim3(512), 0, stream>>>(
        qkh, 262144L, 256,
        qkh + 128, 262144L, 256, vh,
        qkm, 131072L, 128, vm,
        zct, 524288L);

    // comb^T = [zcatT | h^T] @ Wf^T + bfused
    gemm_bf16<<<dim3(8, 6, 32), dim3(256), 0, stream>>>(
        zct, 512, 524288L, hT, 256, 262144L, 512,
        Wf_w, 768, 0L, cmb, 768, 786432L, 768, bf_w, 1);

    gating<<<dim3(32, 32), dim3(256), 0, stream>>>(cmb, m, outh, outm);
}

// Round 11
// 243.889 us; speedup vs baseline: 1.2138x; 1.1805x over previous
//
#include <hip/hip_runtime.h>
#include <hip/hip_bf16.h>

typedef __bf16  v8bf __attribute__((ext_vector_type(8)));
typedef float   v4f  __attribute__((ext_vector_type(4)));
typedef float   f4   __attribute__((ext_vector_type(4)));
typedef unsigned short us8 __attribute__((ext_vector_type(8)));
typedef unsigned short us4 __attribute__((ext_vector_type(4)));
typedef unsigned int u32;

#define BATCH 32
#define CDIM  256
#define HW    1024

// ---- shared ws offsets (bytes) -------------------------------------------
#define OFF_HBT 0L
#define OFF_MBT (OFF_HBT + 16777216L)   // m_bfT
#define OFF_QKH (OFF_MBT + 16777216L)   // qk_h  [32][1024][256]
#define OFF_QKM (OFF_QKH + 16777216L)   // k2_m  [32][1024][128]
#define OFF_VH  (OFF_QKM + 8388608L)    // v_h   [32][256][1024]
#define OFF_VM  (OFF_VH  + 16777216L)   // v_m
#define OFF_ZCT (OFF_VM  + 16777216L)   // zcatT [32][1024][512]
#define OFF_W   (OFF_ZCT + 33554432L)   // weights (1933312 shorts)
#define OFF_B   (OFF_W   + 3866624L)    // biases (2944 floats)
#define OFF_CMB OFF_MBT                 // overlay (mT/qkh/qkm/vh dead)
#define WS_TOTAL (OFF_B + 2944L * 4)
// weight sub-offsets (shorts from OFF_W)
#define W_QK  0
#define W_K2  65536
#define W_V   98304
#define W_V2  163840
#define W_M   491520
#define W_ZT  1081344
#define W_F   1343488
// bias sub-offsets (floats from OFF_B)
#define B_QK  0
#define B_K2  256
#define B_V   384
#define B_V2  640
#define B_F   2176

__device__ inline unsigned short f2u(float x) {
    __hip_bfloat16 h = __float2bfloat16(x);
    union { __hip_bfloat16 h; unsigned short u; } cv; cv.h = h; return cv.u;
}
__device__ inline float u2f(unsigned short u) {
    union { unsigned short u; __hip_bfloat16 h; } cv; cv.u = u; return __bfloat162float(cv.h);
}
__device__ inline float sigmoidf_(float x) {
    x = fminf(fmaxf(x, -30.f), 30.f);
    return 1.f / (1.f + __expf(-x));
}
__device__ inline float tanhf_(float x) {
    x = fminf(fmaxf(x, -15.f), 15.f);
    float e = __expf(2.f * x);
    return (e - 1.f) / (e + 1.f);
}
// direct global->LDS DMA, 16B per lane; lds dest is wave-uniform base + lane*16
__device__ inline void glds16(const unsigned short* g, unsigned short* l) {
    __builtin_amdgcn_global_load_lds(
        (const __attribute__((address_space(1))) u32*)g,
        (__attribute__((address_space(3))) u32*)l, 16, 0, 0);
}

// ---------------------------------------------------------------------------
// prep: weight pack (blocks 0..6024) + bias fold (6025..6027) +
//       transposing fp32->bf16 convert of h,m (6028..10123).
// ---------------------------------------------------------------------------
__global__ __launch_bounds__(256)
void prep(const float* __restrict__ hsrc, const float* __restrict__ msrc,
          const float* __restrict__ Wq, const float* __restrict__ Wk,
          const float* __restrict__ Wv, const float* __restrict__ Wk2,
          const float* __restrict__ Wv2, const float* __restrict__ Wz,
          const float* __restrict__ Wm,
          const float* __restrict__ bq, const float* __restrict__ bk,
          const float* __restrict__ bk2, const float* __restrict__ bv,
          const float* __restrict__ bv2, const float* __restrict__ bz,
          const float* __restrict__ bm,
          char* __restrict__ ws)
{
    __shared__ float t[64][68];
    unsigned short* wdst = (unsigned short*)(ws + OFF_W);
    float*          bdst = (float*)(ws + OFF_B);
    const int bid = blockIdx.x;
    const int tid = threadIdx.x;

    if (bid < 6025) {                       // ---- weight pack
        const int gid = bid * 256 + tid;
        if (gid < 1081344) {
            const float* s; int off;
            if      (gid <   32768) { s = Wq;  off = gid; }
            else if (gid <   65536) { s = Wk;  off = gid -   32768; }
            else if (gid <   98304) { s = Wk2; off = gid -   65536; }
            else if (gid <  163840) { s = Wv;  off = gid -   98304; }
            else if (gid <  229376) { s = Wv2; off = gid -  163840; }
            else if (gid <  491520) { s = Wz;  off = gid -  229376; }
            else                    { s = Wm;  off = gid -  491520; }
            wdst[gid] = f2u(s[off]);
        } else if (gid < 1343488) {
            const int idx = gid - 1081344;          // WzT[k][j] = Wz[j][k]
            const int k = idx >> 9, j = idx & 511;
            wdst[gid] = f2u(Wz[j * 512 + k]);
        } else if (gid < 1540096) {
            const int idx = gid - 1343488;          // Wf[o][512+r] = Wm[o][512+r]
            const int o = idx >> 8, kk = 512 + (idx & 255);
            wdst[W_F + o * 768 + kk] = f2u(Wm[o * 768 + kk]);
        } else {
            const int bi = gid - 1540096;
            if (bi < 2176) {
                const float* s; int off;
                if      (bi <  128) { s = bq;  off = bi; }
                else if (bi <  256) { s = bk;  off = bi -  128; }
                else if (bi <  384) { s = bk2; off = bi -  256; }
                else if (bi <  640) { s = bv;  off = bi -  384; }
                else if (bi <  896) { s = bv2; off = bi -  640; }
                else if (bi < 1408) { s = bz;  off = bi -  896; }
                else                { s = bm;  off = bi - 1408; }
                bdst[bi] = s[off];
            }
        }
    } else if (bid < 6028) {                // ---- bfused = bm + Wm[:, :512] @ bz
        const int o = (bid - 6025) * 256 + tid;
        if (o < 768) {
            float s = bm[o];
            const float* r = Wm + (long)o * 768;
#pragma unroll 8
            for (int j = 0; j < 512; ++j) s += r[j] * bz[j];
            bdst[B_F + o] = s;
        }
    } else {                                // ---- transpose_cvt
        const int tz = bid - 6028;          // 0..4095
        const int z  = tz >> 6;             // 0..63
        const int p0 = (tz & 15) * 64;
        const int c0 = ((tz >> 4) & 3) * 64;
        const float* src = (z < BATCH) ? hsrc + (long)z * CDIM * HW
                                       : msrc + (long)(z - BATCH) * CDIM * HW;
        unsigned short* dst = (unsigned short*)(ws + ((z < BATCH) ? OFF_HBT : OFF_MBT))
                              + (long)((z < BATCH) ? z : z - BATCH) * HW * CDIM;
        const int r  = tid >> 4;
        const int c4 = (tid & 15) * 4;
#pragma unroll
        for (int i = 0; i < 4; ++i) {
            const f4 v = *reinterpret_cast<const f4*>(src + (long)(c0 + r + 16 * i) * HW + p0 + c4);
            t[r + 16 * i][c4 + 0] = v[0];
            t[r + 16 * i][c4 + 1] = v[1];
            t[r + 16 * i][c4 + 2] = v[2];
            t[r + 16 * i][c4 + 3] = v[3];
        }
        __syncthreads();
#pragma unroll
        for (int i = 0; i < 4; ++i) {
            const int pr = r + 16 * i;
            us4 o;
#pragma unroll
            for (int j = 0; j < 4; ++j) o[j] = f2u(t[c4 + j][pr]);
            *reinterpret_cast<us4*>(dst + (long)(p0 + pr) * CDIM + c0 + c4) = o;
        }
    }
}

// ---------------------------------------------------------------------------
// Shared GEMM core: 128x128 tile, BK=64, st-swizzled LDS (linear dest,
// inverse-swizzled global source, swizzled ds_read).
// ---------------------------------------------------------------------------
__device__ __forceinline__
void gemm_core(const unsigned short* __restrict__ A, int lda,
               const unsigned short* __restrict__ A2, int lda2, int kswitch,
               const unsigned short* __restrict__ Bt, int ldb,
               unsigned short* __restrict__ Cp, int ldc,
               int K, const float* __restrict__ bias, int biasMode,
               int m0, int n0,
               unsigned short* As, unsigned short* Bs)
{
    const int tid  = threadIdx.x;
    const int lane = tid & 63;
    const int w    = tid >> 6;

    v4f acc[4][4];
#pragma unroll
    for (int i = 0; i < 4; ++i)
#pragma unroll
        for (int j = 0; j < 4; ++j) acc[i][j] = v4f{0.f, 0.f, 0.f, 0.f};

    const int wm   = (w >> 1) * 64;
    const int wn   = (w & 1) * 64;
    const int fr   = lane & 15;
    const int g    = lane >> 4;

    const int arow = (w << 3) + (lane >> 3);
    const int acol = (((lane & 7) ^ ((lane >> 3) & 7)) * 8);
    const int lbase = (w << 9);

    for (int k0 = 0; k0 < K; k0 += 64) {
        const unsigned short* Ab; int Al; int Ao;
        if (k0 < kswitch) { Ab = A;  Al = lda;  Ao = k0; }
        else              { Ab = A2; Al = lda2; Ao = k0 - kswitch; }
        const unsigned short* ga = Ab + (long)(m0 + arow) * Al + Ao + acol;
        const unsigned short* gb = Bt + (long)(n0 + arow) * ldb + k0 + acol;
#pragma unroll
        for (int i = 0; i < 4; ++i) {
            glds16(ga + (long)(32 * i) * Al, &As[i * 2048 + lbase]);
            glds16(gb + (long)(32 * i) * ldb, &Bs[i * 2048 + lbase]);
        }
        __syncthreads();
#pragma unroll
        for (int ks = 0; ks < 2; ++ks) {
            const int slot = ((ks * 4 + g) ^ (fr & 7)) * 8;
            v8bf af[4], bfv[4];
#pragma unroll
            for (int mi = 0; mi < 4; ++mi)
                af[mi] = *reinterpret_cast<const v8bf*>(&As[(wm + mi * 16 + fr) * 64 + slot]);
#pragma unroll
            for (int ni = 0; ni < 4; ++ni)
                bfv[ni] = *reinterpret_cast<const v8bf*>(&Bs[(wn + ni * 16 + fr) * 64 + slot]);
#pragma unroll
            for (int mi = 0; mi < 4; ++mi)
#pragma unroll
                for (int ni = 0; ni < 4; ++ni)
                    acc[mi][ni] = __builtin_amdgcn_mfma_f32_16x16x32_bf16(af[mi], bfv[ni], acc[mi][ni], 0, 0, 0);
        }
        __syncthreads();
    }

    const int rbase0 = m0 + wm + g * 4;
#pragma unroll
    for (int mi = 0; mi < 4; ++mi) {
#pragma unroll
        for (int ni = 0; ni < 4; ++ni) {
            const int col = n0 + wn + ni * 16 + fr;
            const int rb  = rbase0 + mi * 16;
            const float bn = (biasMode == 1) ? bias[col] : 0.f;
#pragma unroll
            for (int r = 0; r < 4; ++r) {
                float x = acc[mi][ni][r] + bn;
                if (biasMode == 2) x += bias[rb + r];
                Cp[(long)(rb + r) * ldc + col] = f2u(x);
            }
        }
    }
}

// 5 GEMM jobs in one dispatch (1816 blocks, all operands inside ws):
//  j0 [0,512):    qk_h  = hT @ Wqk^T + bqk      (8x2 tiles x 32 b)
//  j1 [512,768):  k2_m  = mT @ Wk2^T + bk2      (8x1 x 32)
//  j2 [768,1280): v_h   = Wv @ hT^T + bv[m]     (2x8 x 32)
//  j3 [1280,1792): v_m  = Wv2 @ mT^T + bv2[m]   (2x8 x 32)
//  j4 [1792,1816): Wf[:, :512] = Wm[:, :512] @ Wz  (6x4 x 1)
__global__ __launch_bounds__(256)
void gemm_multi(char* __restrict__ ws)
{
    __shared__ unsigned short As[128 * 64];
    __shared__ unsigned short Bs[128 * 64];
    unsigned short* wA = (unsigned short*)(ws + OFF_W);
    float*          bA = (float*)(ws + OFF_B);
    const int id = blockIdx.x;

    if (id < 512) {
        const int b = id >> 4, x = id & 7, y = (id >> 3) & 1;
        const unsigned short* A = (unsigned short*)(ws + OFF_HBT) + (long)b * 262144;
        gemm_core(A, 256, A, 256, 1 << 30, wA + W_QK, 256,
                  (unsigned short*)(ws + OFF_QKH) + (long)b * 262144, 256,
                  256, bA + B_QK, 1, x * 128, y * 128, As, Bs);
    } else if (id < 768) {
        const int idx = id - 512, b = idx >> 3, x = idx & 7;
        const unsigned short* A = (unsigned short*)(ws + OFF_MBT) + (long)b * 262144;
        gemm_core(A, 256, A, 256, 1 << 30, wA + W_K2, 256,
                  (unsigned short*)(ws + OFF_QKM) + (long)b * 131072, 128,
                  256, bA + B_K2, 1, x * 128, 0, As, Bs);
    } else if (id < 1280) {
        const int idx = id - 768, b = idx >> 4, x = idx & 1, y = (idx >> 1) & 7;
        gemm_core(wA + W_V, 256, wA + W_V, 256, 1 << 30,
                  (unsigned short*)(ws + OFF_HBT) + (long)b * 262144, 256,
                  (unsigned short*)(ws + OFF_VH) + (long)b * 262144, 1024,
                  256, bA + B_V, 2, x * 128, y * 128, As, Bs);
    } else if (id < 1792) {
        const int idx = id - 1280, b = idx >> 4, x = idx & 1, y = (idx >> 1) & 7;
        gemm_core(wA + W_V2, 256, wA + W_V2, 256, 1 << 30,
                  (unsigned short*)(ws + OFF_MBT) + (long)b * 262144, 256,
                  (unsigned short*)(ws + OFF_VM) + (long)b * 262144, 1024,
                  256, bA + B_V2, 2, x * 128, y * 128, As, Bs);
    } else {
        const int idx = id - 1792, x = idx % 6, y = idx / 6;
        gemm_core(wA + W_M, 768, wA + W_M, 768, 1 << 30, wA + W_ZT, 512,
                  wA + W_F, 768, 512, bA, 0, x * 128, y * 128, As, Bs);
    }
}

__global__ __launch_bounds__(256)
void gemm_bf16(const unsigned short* __restrict__ A, int lda, long sA,
               const unsigned short* __restrict__ A2, int lda2, long sA2, int kswitch,
               const unsigned short* __restrict__ Bt, int ldb, long sB,
               unsigned short* __restrict__ Cp, int ldc, long sC,
               int K, const float* __restrict__ bias, int biasMode)
{
    __shared__ unsigned short As[128 * 64];
    __shared__ unsigned short Bs[128 * 64];
    const int b = blockIdx.z;
    gemm_core(A + (long)b * sA, lda, A2 + (long)b * sA2, lda2, kswitch,
              Bt + (long)b * sB, ldb, Cp + (long)b * sC, ldc,
              K, bias, biasMode, blockIdx.x * 128, blockIdx.y * 128, As, Bs);
}

// ---------------------------------------------------------------------------
// Fused attention v6b: as v6 (64-p tiles, Q in LDS, 2 blocks/CU, (512,4))
// + full-rank P swizzle: t(p) = (p&7) ^ ((p>>3)&1)*3 makes the wave's 4
// g-subgroup rows map to 4 DISTINCT bank masks (R10: writes were 4-way
// conflicted because (p&7) repeats for rows 8 apart -> 6.29M conflicts).
// ---------------------------------------------------------------------------
__global__ __launch_bounds__(512, 4)
void attn_fused(const unsigned short* __restrict__ Qb, long sQ, int ldq,
                const unsigned short* __restrict__ K0, long sK0, int ldk0,
                const unsigned short* __restrict__ V0,
                const unsigned short* __restrict__ K1, long sK1, int ldk1,
                const unsigned short* __restrict__ V1,
                unsigned short* __restrict__ Out, long sO)
{
    __shared__ unsigned short Qs[64 * 128];   // 16 KB
    __shared__ unsigned short Ks[64 * 128];   // 16 KB
    __shared__ unsigned short Vs[256 * 64];   // 32 KB
    __shared__ unsigned short Ps[64 * 64];    //  8 KB

    const int id = blockIdx.x;            // 0..1023
    const int c8 = id & 7;
    const int k  = id >> 3;               // 0..127
    const int z  = c8 * 8 + (k >> 4);     // (branch,batch)
    const int p0 = (k & 15) * 64;

    const int b  = (z < 32) ? z : z - 32;
    const unsigned short* Kp; const unsigned short* Vp; int ldk, outoff;
    if (z < 32) { Kp = K0 + (long)b * sK0; Vp = V0 + (long)b * 262144L; ldk = ldk0; outoff = 0; }
    else        { Kp = K1 + (long)b * sK1; Vp = V1 + (long)b * 262144L; ldk = ldk1; outoff = 256; }
    const unsigned short* Qp = Qb + (long)b * sQ;
    Out += (long)b * sO;

    const int tid  = threadIdx.x;
    const int lane = tid & 63;
    const int w    = tid >> 6;
    const int fr   = lane & 15;
    const int g    = lane >> 4;
    const int wp   = w >> 2;     // p-half (32 rows)
    const int wq   = w & 3;      // kv-quarter (S) / c-quarter (PV)

    v4f vacc[2][4];
#pragma unroll
    for (int i = 0; i < 2; ++i)
#pragma unroll
        for (int j = 0; j < 4; ++j) vacc[i][j] = v4f{0.f, 0.f, 0.f, 0.f};
    float rp[2][4];
#pragma unroll
    for (int i = 0; i < 2; ++i)
#pragma unroll
        for (int r = 0; r < 4; ++r) rp[i][r] = 0.f;

    const int srow   = tid >> 4;                          // 0..31
    const int schunk = ((tid & 15) ^ (srow & 7)) * 8;
    const int vrow   = tid >> 3;                          // 0..63
    const int vchunk = ((tid & 7) ^ (vrow & 7)) * 8;
    const int sdst   = w * 512;
    const int kr     = wq * 16 + fr;                      // K row for S

#define TSWZ(p) (((p) & 7) ^ ((((p) >> 3) & 1) * 3))

#define STAGE_Q()                                                              \
    { _Pragma("unroll")                                                        \
      for (int i = 0; i < 2; ++i)                                              \
          glds16(Qp + (long)(p0 + i * 32 + srow) * ldq + schunk,               \
                 &Qs[i * 4096 + sdst]); }
#define STAGE_K(t)                                                             \
    { const int kv0 = (t) * 64;                                                \
      _Pragma("unroll")                                                        \
      for (int i = 0; i < 2; ++i)                                              \
          glds16(Kp + (long)(kv0 + i * 32 + srow) * ldk + schunk,              \
                 &Ks[i * 4096 + sdst]); }
#define STAGE_V(t)                                                             \
    { const int kv0 = (t) * 64;                                                \
      _Pragma("unroll")                                                        \
      for (int i = 0; i < 4; ++i)                                              \
          glds16(Vp + (long)(i * 64 + vrow) * 1024 + kv0 + vchunk,             \
                 &Vs[i * 4096 + sdst]); }

    STAGE_Q();
    STAGE_K(0);

    for (int t = 0; t < 16; ++t) {
        __syncthreads();              // drains Q(+K0) / K(t); PV(t-1) LDS reads done
        STAGE_V(t);                   // drained at barrier-2, covered by S+exp

        // ---- S = Q @ K^T (per wave: 32p x 16kv), exp, write P
        v4f sacc[2];
#pragma unroll
        for (int mi = 0; mi < 2; ++mi) sacc[mi] = v4f{0.f, 0.f, 0.f, 0.f};
        __builtin_amdgcn_s_setprio(1);
#pragma unroll
        for (int ks = 0; ks < 4; ++ks) {
            const v8bf kf = *reinterpret_cast<const v8bf*>(
                &Ks[kr * 128 + ((ks * 4 + g) ^ (kr & 7)) * 8]);
#pragma unroll
            for (int mi = 0; mi < 2; ++mi) {
                const int qrow = wp * 32 + mi * 16 + fr;
                const v8bf qf = *reinterpret_cast<const v8bf*>(
                    &Qs[qrow * 128 + ((ks * 4 + g) ^ (qrow & 7)) * 8]);
                sacc[mi] = __builtin_amdgcn_mfma_f32_16x16x32_bf16(qf, kf, sacc[mi], 0, 0, 0);
            }
        }
        __builtin_amdgcn_s_setprio(0);
#pragma unroll
        for (int mi = 0; mi < 2; ++mi)
#pragma unroll
            for (int r = 0; r < 4; ++r) {
                const float e = __expf(sacc[mi][r]);
                rp[mi][r] += e;
                const int prow = wp * 32 + mi * 16 + g * 4 + r;
                Ps[prow * 64 + (kr ^ (TSWZ(prow) << 3))] = f2u(e);
            }

        __syncthreads();              // drains V(t); Ps visible; Ks reads done
        if (t < 15) STAGE_K(t + 1);   // drained at barrier-1(t+1), covered by PV

        // ---- PV: vacc += P @ V^T (per wave: 32p x 64c, K=64)
        __builtin_amdgcn_s_setprio(1);
#pragma unroll
        for (int ks = 0; ks < 2; ++ks) {
            v8bf pf[2], vf[4];
#pragma unroll
            for (int mi = 0; mi < 2; ++mi) {
                const int pr = wp * 32 + mi * 16 + fr;
                pf[mi] = *reinterpret_cast<const v8bf*>(
                    &Ps[pr * 64 + ((ks * 4 + g) ^ TSWZ(pr)) * 8]);
            }
#pragma unroll
            for (int ni = 0; ni < 4; ++ni) {
                const int vr = wq * 64 + ni * 16 + fr;
                vf[ni] = *reinterpret_cast<const v8bf*>(
                    &Vs[vr * 64 + ((ks * 4 + g) ^ (vr & 7)) * 8]);
            }
#pragma unroll
            for (int mi = 0; mi < 2; ++mi)
#pragma unroll
                for (int ni = 0; ni < 4; ++ni)
                    vacc[mi][ni] = __builtin_amdgcn_mfma_f32_16x16x32_bf16(pf[mi], vf[ni], vacc[mi][ni], 0, 0, 0);
        }
        __builtin_amdgcn_s_setprio(0);
    }
#undef STAGE_Q
#undef STAGE_K
#undef STAGE_V
#undef TSWZ

    __syncthreads();
    // rowsum: 16 fr-lanes via shfl; 4 wq-waves via LDS (red[4][64] over Ps)
    float* red = reinterpret_cast<float*>(Ps);
#pragma unroll
    for (int mi = 0; mi < 2; ++mi)
#pragma unroll
        for (int r = 0; r < 4; ++r) {
            float v = rp[mi][r];
            v += __shfl_xor(v, 1);
            v += __shfl_xor(v, 2);
            v += __shfl_xor(v, 4);
            v += __shfl_xor(v, 8);
            if (fr == 0) red[wq * 64 + wp * 32 + mi * 16 + g * 4 + r] = v;
        }
    __syncthreads();

#pragma unroll
    for (int mi = 0; mi < 2; ++mi)
#pragma unroll
        for (int r = 0; r < 4; ++r) {
            const int pl = wp * 32 + mi * 16 + g * 4 + r;
            const float inv = 1.f / (red[pl] + red[64 + pl] + red[128 + pl] + red[192 + pl]);
#pragma unroll
            for (int ni = 0; ni < 4; ++ni)
                Out[(long)(p0 + pl) * 512 + outoff + wq * 64 + ni * 16 + fr]
                    = f2u(vacc[mi][ni][r] * inv);
        }
}

// ---------------------------------------------------------------------------
// Gating epilogue.
// ---------------------------------------------------------------------------
__global__ __launch_bounds__(256)
void gating(const unsigned short* __restrict__ combT, const float* __restrict__ m,
            float* __restrict__ outh, float* __restrict__ outm)
{
    const int b  = blockIdx.y;
    const int p0 = blockIdx.x * 32;
    __shared__ unsigned short t[32 * 776];
    const unsigned short* src = combT + ((long)b * HW + p0) * 768;
    const int tid = threadIdx.x;
    for (int i = tid; i < 32 * 96; i += 256) {
        const int rr = i / 96;
        const int cc = (i % 96) * 8;
        *reinterpret_cast<us8*>(&t[rr * 776 + cc]) =
            *reinterpret_cast<const us8*>(src + (long)rr * 768 + cc);
    }
    __syncthreads();
    const int pl = tid & 31;
    const int cl = tid >> 5;
    for (int ci = 0; ci < 32; ++ci) {
        const int c = ci * 8 + cl;
        const float mo = u2f(t[pl * 776 + c]);
        const float mg = u2f(t[pl * 776 + 256 + c]);
        const float mi = u2f(t[pl * 776 + 512 + c]);
        const long gi = ((long)b * CDIM + c) * HW + p0 + pl;
        const float mv = m[gi];
        const float ms = sigmoidf_(mi);
        const float nm = (1.f - ms) * mv + ms * tanhf_(mg);
        const float nh = sigmoidf_(mo) * nm;
        outh[gi] = nh;
        outm[gi] = nm;
    }
}

// ---------------------------------------------------------------------------
extern "C" void kernel_launch(void* const* d_in, const int* in_sizes, int n_in,
                              void* d_out, int out_size, void* d_ws, size_t ws_size,
                              hipStream_t stream)
{
    const float* h   = (const float*)d_in[0];
    const float* m   = (const float*)d_in[1];
    const float* Wq  = (const float*)d_in[2];
    const float* bq  = (const float*)d_in[3];
    const float* Wk  = (const float*)d_in[4];
    const float* bk  = (const float*)d_in[5];
    const float* Wv  = (const float*)d_in[6];
    const float* bv  = (const float*)d_in[7];
    const float* Wk2 = (const float*)d_in[8];
    const float* bk2 = (const float*)d_in[9];
    const float* Wv2 = (const float*)d_in[10];
    const float* bv2 = (const float*)d_in[11];
    const float* Wz  = (const float*)d_in[12];
    const float* bz  = (const float*)d_in[13];
    const float* Wm  = (const float*)d_in[14];
    const float* bm  = (const float*)d_in[15];

    char* ws = (char*)d_ws;
    if (ws_size < (size_t)WS_TOTAL) return;

    unsigned short* hT  = (unsigned short*)(ws + OFF_HBT);
    unsigned short* qkh = (unsigned short*)(ws + OFF_QKH);
    unsigned short* qkm = (unsigned short*)(ws + OFF_QKM);
    unsigned short* vh  = (unsigned short*)(ws + OFF_VH);
    unsigned short* vm  = (unsigned short*)(ws + OFF_VM);
    unsigned short* zct = (unsigned short*)(ws + OFF_ZCT);
    unsigned short* cmb = (unsigned short*)(ws + OFF_CMB);
    unsigned short* wA  = (unsigned short*)(ws + OFF_W);
    float*          bA  = (float*)(ws + OFF_B);

    float* outh = (float*)d_out;
    float* outm = outh + 8388608L;

    // pack + bias-fold + transpose in ONE dispatch
    prep<<<dim3(10124), dim3(256), 0, stream>>>(
        h, m, Wq, Wk, Wv, Wk2, Wv2, Wz, Wm,
        bq, bk, bk2, bv, bv2, bz, bm, ws);

    // 5 GEMM jobs (projections, v's, Wf fold) in ONE dispatch
    gemm_multi<<<dim3(1816), dim3(256), 0, stream>>>(ws);

    // fused attention, both branches, XCD-swizzled 1D grid (64-p tiles)
    attn_fused<<<dim3(1024), dim3(512), 0, stream>>>(
        qkh, 262144L, 256,
        qkh + 128, 262144L, 256, vh,
        qkm, 131072L, 128, vm,
        zct, 524288L);

    // comb^T = [zcatT | h^T] @ Wf^T + bfused
    gemm_bf16<<<dim3(8, 6, 32), dim3(256), 0, stream>>>(
        zct, 512, 524288L, hT, 256, 262144L, 512,
        wA + W_F, 768, 0L, cmb, 768, 786432L, 768, bA + B_F, 1);

    gating<<<dim3(32, 32), dim3(256), 0, stream>>>(cmb, m, outh, outm);
}